// Round 7
// baseline (151.589 us; speedup 1.0000x reference)
//
#include <hip/hip_runtime.h>

#define H   128
#define P   16             // points per block (= MFMA N)
#define NT  512            // 8 waves: wave = plg*4 + jw  (plg: 3 planes, jw: 32 j)

typedef _Float16 v8h __attribute__((ext_vector_type(8)));
typedef __fp16   h2  __attribute__((ext_vector_type(2)));   // cvt_pkrtz return type
typedef float    v4f __attribute__((ext_vector_type(4)));
typedef float    v2f __attribute__((ext_vector_type(2)));   // -> VOP3P v_pk_*_f32

union PK2 { h2 h[2]; uint2 u; };       // 4 f16 = 8 B

// State plane layout: [pl][p][k], 128 f16 per row, XOR-octet swizzle; returns
// f16 index of octet o of row p. (p&15 == p at P=16.)
__device__ __forceinline__ int soct(int pl, int p, int o) {
    return ((pl * P + p) * 16 + (o ^ (p & 15))) << 3;
}

// Aux exchange (f32): [jw][pl3][pt16][j32], XOR-swizzled j-group to spread banks.
__device__ __forceinline__ int axi(int jw, int pp, int pt, int jb) {
    return ((jw * 3 + pp) * 16 + pt) * 32 + (jb ^ ((pt & 7) << 2));
}

// Prepass (free): Wt in MFMA A-fragment physical order ws[l][oct][j][8],
// oct = k>>3. Main kernel loads A fragments directly from this buffer into
// registers (64 KB, L2-resident) — A never touches LDS.
__global__ void wt_convert(const float* __restrict__ W1,
                           const float* __restrict__ W2,
                           _Float16* __restrict__ ws) {
    const int t = blockIdx.x * 64 + threadIdx.x;   // 0..16383 (u32 units)
    const int l = t >> 13;
    const int r = t & 8191;
    const int oct = r >> 9;
    const int rem = r & 511;
    const int j  = rem >> 2;
    const int wp = rem & 3;
    const int k  = oct * 8 + 2 * wp;
    const float* __restrict__ W = l ? W2 : W1;
    const float a = W[k * H + j];
    const float b = W[(k + 1) * H + j];
    union { h2 h; unsigned u; } q;
    q.h = __builtin_amdgcn_cvt_pkrtz(a, b);
    ((unsigned*)ws)[t] = q.u;
}

// Packed-pair tanh + derivatives: exp/rcp scalar, fma chain packed (VOP3P).
__device__ __forceinline__ v2f tanh_d2_p(v2f z, v2f& g1, v2f& g2) {
    v2f r;
    r.x = __builtin_amdgcn_rcpf(__expf(2.f * z.x) + 1.f);
    r.y = __builtin_amdgcn_rcpf(__expf(2.f * z.y) + 1.f);
    const v2f a = -2.f * r + 1.f;                  // e=inf -> r=0 -> a=1
    g1 = 1.f - a * a;
    g2 = -2.f * (a * g1);
    return a;
}

// R24 (resubmit; round-6 run died in container acquisition, no kernel signal).
// Plane-split waves — break the D-vs-occupancy deadlock.
// Measured walls: <=4 waves/SIMD = stall-bound (R17/R21/R22, 72-75us, pipes
// 30-50%); 8 waves/SIMD with j-split (R23) = LDS-read-bound (24 B-b128/pt,
// 147k cy/CU = 85% of runtime, dur still 72us). Constraint: D = 128/j_wave
// duplication vs C = (j/16)*pl*4 regs vs 64-VGPR 8-wave tier.
// Fix: wave = (jw 32 j, plg 3 planes): C = 2mt*3pl*4 = 24 regs (64-tier kept)
// at D=4 -> 12 B-reads/pt (+3 aux) ~= 92k cy/CU, off the critical path.
// Chain rule needs all 6 planes: plg0 (z,tx,ty) writes raw C to f32 aux;
// plg1 (cx,cm,cy) reads aux, recomputes tanh in parallel, does s3-5.
// LDS 48KB/block -> 3 blocks/CU x 8 waves = 6 waves/SIMD.
// Tripwire: VGPR>64 or WRITE_SIZE>>MB = spill -> structure dead.
__global__ __launch_bounds__(NT, 8)
void pinn_hess_mfma(const float* __restrict__ X,
                    const float* __restrict__ W0, const float* __restrict__ b0,
                    const _Float16* __restrict__ Wt,
                    const float* __restrict__ b1, const float* __restrict__ b2,
                    const float* __restrict__ W3,
                    float* __restrict__ out, int N)
{
    __shared__ _Float16 sS[6 * P * H];        // 24576 B, swizzled state planes
    __shared__ float    sAux[4 * 3 * P * 32]; // 24576 B, f32 {z,tx,ty} exchange

    const int tid   = threadIdx.x;
    const int wave  = tid >> 6;
    const int plg   = wave >> 2;              // 0: planes 0-2, 1: planes 3-5
    const int jw    = wave & 3;               // j range jw*32..+32
    const int lane  = tid & 63;
    const int quad  = lane >> 4;
    const int l15   = lane & 15;
    const int pbase = blockIdx.x * P;
    const int pmy   = l15;                    // this lane's point row (GEMM n)

    // ---------------- layer 0 (input dim 2, analytic); 512 tasks = 1/thread --
    {
        const int p = tid >> 5, q4 = tid & 31;
        const float x = X[2 * (pbase + p)];
        const float y = X[2 * (pbase + p) + 1];
        const float4 wx4 = *(const float4*)&W0[q4 * 4];
        const float4 wy4 = *(const float4*)&W0[H + q4 * 4];
        const float4 bb4 = *(const float4*)&b0[q4 * 4];
        PK2 q[6];
        #pragma unroll
        for (int hp = 0; hp < 2; ++hp) {       // j-pairs, packed math
            const v2f wx = hp ? (v2f){wx4.z, wx4.w} : (v2f){wx4.x, wx4.y};
            const v2f wy = hp ? (v2f){wy4.z, wy4.w} : (v2f){wy4.x, wy4.y};
            const v2f bb = hp ? (v2f){bb4.z, bb4.w} : (v2f){bb4.x, bb4.y};
            v2f g1, g2;
            const v2f a = tanh_d2_p(x * wx + y * wy + bb, g1, g2);
            const v2f gx = g2 * wx;
            const v2f r0 = a,        r1 = g1 * wx,  r2 = g1 * wy;
            const v2f r3 = gx * wx,  r4 = gx * wy,  r5 = (g2 * wy) * wy;
            q[0].h[hp] = __builtin_amdgcn_cvt_pkrtz(r0.x, r0.y);
            q[1].h[hp] = __builtin_amdgcn_cvt_pkrtz(r1.x, r1.y);
            q[2].h[hp] = __builtin_amdgcn_cvt_pkrtz(r2.x, r2.y);
            q[3].h[hp] = __builtin_amdgcn_cvt_pkrtz(r3.x, r3.y);
            q[4].h[hp] = __builtin_amdgcn_cvt_pkrtz(r4.x, r4.y);
            q[5].h[hp] = __builtin_amdgcn_cvt_pkrtz(r5.x, r5.y);
        }
        const int o  = q4 >> 1;                // octet
        const int ho = (q4 & 1) * 4;           // half-offset within octet
        #pragma unroll
        for (int pl = 0; pl < 6; ++pl)
            *(uint2*)&sS[soct(pl, p, o) + ho] = q[pl].u;
    }

    // A-fragment base (v8h units): [oct = kc*4+quad][j][8]; +16 for m-tile 1
    const int aoff = quad * H + jw * 32 + l15;

    // ---------------- hidden layers ----------------
    #pragma unroll
    for (int layer = 0; layer < 2; ++layer) {
        const v8h* __restrict__ Ag = (const v8h*)(Wt + layer * (16 * H * 8));

        __syncthreads();   // bar A: sS writes visible
        __builtin_amdgcn_sched_barrier(0);

        v4f C[2][3];       // [mt][plane-within-group]
        #pragma unroll
        for (int mt = 0; mt < 2; ++mt)
            #pragma unroll
            for (int pp = 0; pp < 3; ++pp) C[mt][pp] = (v4f){0, 0, 0, 0};

        #pragma unroll
        for (int kc = 0; kc < 4; ++kc) {
            const v8h A0 = Ag[aoff + kc * 4 * H];
            const v8h A1 = Ag[aoff + kc * 4 * H + 16];
            const int oct = kc * 4 + quad;
            #pragma unroll
            for (int pp = 0; pp < 3; ++pp) {
                const v8h B = *(const v8h*)&sS[soct(plg * 3 + pp, pmy, oct)];
                C[0][pp] = __builtin_amdgcn_mfma_f32_16x16x32_f16(A0, B, C[0][pp], 0, 0, 0);
                C[1][pp] = __builtin_amdgcn_mfma_f32_16x16x32_f16(A1, B, C[1][pp], 0, 0, 0);
            }
            __builtin_amdgcn_sched_barrier(0);  // bound A/B regs in flight
        }

        __syncthreads();   // bar B: all GEMM reads of sS done

        // plg0 exports raw {z,tx,ty} (f32) for plg1's chain rule
        if (plg == 0) {
            #pragma unroll
            for (int mt = 0; mt < 2; ++mt) {
                const int jb = mt * 16 + quad * 4;     // wave-local j-group
                #pragma unroll
                for (int pp = 0; pp < 3; ++pp)
                    *(v4f*)&sAux[axi(jw, pp, l15, jb)] = C[mt][pp];
            }
        }
        __syncthreads();   // bar C: aux visible

        if (layer == 0) {
            if (plg == 0) {
                // states s0,s1,s2 = a, g1*tx, g1*ty  (all operands in regs)
                #pragma unroll
                for (int mt = 0; mt < 2; ++mt) {
                    const int j0 = jw * 32 + mt * 16 + quad * 4;
                    const float4 bv = *(const float4*)&b1[j0];
                    PK2 q[3];
                    #pragma unroll
                    for (int hp = 0; hp < 2; ++hp) {
                        const v2f zb = hp ? (v2f){C[mt][0][2], C[mt][0][3]}
                                          : (v2f){C[mt][0][0], C[mt][0][1]};
                        const v2f bb = hp ? (v2f){bv.z, bv.w} : (v2f){bv.x, bv.y};
                        const v2f tx = hp ? (v2f){C[mt][1][2], C[mt][1][3]}
                                          : (v2f){C[mt][1][0], C[mt][1][1]};
                        const v2f ty = hp ? (v2f){C[mt][2][2], C[mt][2][3]}
                                          : (v2f){C[mt][2][0], C[mt][2][1]};
                        v2f g1, g2;
                        const v2f a  = tanh_d2_p(zb + bb, g1, g2);
                        const v2f s1 = g1 * tx, s2 = g1 * ty;
                        q[0].h[hp] = __builtin_amdgcn_cvt_pkrtz(a.x,  a.y);
                        q[1].h[hp] = __builtin_amdgcn_cvt_pkrtz(s1.x, s1.y);
                        q[2].h[hp] = __builtin_amdgcn_cvt_pkrtz(s2.x, s2.y);
                    }
                    const int ob = j0 >> 3;
                    const int ho = (quad & 1) * 4;
                    #pragma unroll
                    for (int pl = 0; pl < 3; ++pl)
                        *(uint2*)&sS[soct(pl, pmy, ob) + ho] = q[pl].u;
                }
            } else {
                // states s3,s4,s5 from aux {z,tx,ty} + own {cx,cm,cy}
                #pragma unroll
                for (int mt = 0; mt < 2; ++mt) {
                    const int jb = mt * 16 + quad * 4;
                    const int j0 = jw * 32 + jb;
                    const v4f zv  = *(const v4f*)&sAux[axi(jw, 0, l15, jb)];
                    const v4f txv = *(const v4f*)&sAux[axi(jw, 1, l15, jb)];
                    const v4f tyv = *(const v4f*)&sAux[axi(jw, 2, l15, jb)];
                    const float4 bv = *(const float4*)&b1[j0];
                    PK2 q[3];
                    #pragma unroll
                    for (int hp = 0; hp < 2; ++hp) {
                        const v2f zb = hp ? (v2f){zv[2], zv[3]}   : (v2f){zv[0], zv[1]};
                        const v2f bb = hp ? (v2f){bv.z, bv.w}     : (v2f){bv.x, bv.y};
                        const v2f tx = hp ? (v2f){txv[2], txv[3]} : (v2f){txv[0], txv[1]};
                        const v2f ty = hp ? (v2f){tyv[2], tyv[3]} : (v2f){tyv[0], tyv[1]};
                        const v2f cx = hp ? (v2f){C[mt][0][2], C[mt][0][3]}
                                          : (v2f){C[mt][0][0], C[mt][0][1]};
                        const v2f cm = hp ? (v2f){C[mt][1][2], C[mt][1][3]}
                                          : (v2f){C[mt][1][0], C[mt][1][1]};
                        const v2f cy = hp ? (v2f){C[mt][2][2], C[mt][2][3]}
                                          : (v2f){C[mt][2][0], C[mt][2][1]};
                        v2f g1, g2;
                        tanh_d2_p(zb + bb, g1, g2);
                        const v2f gx = g2 * tx;
                        const v2f s3 = gx * tx + g1 * cx;
                        const v2f s4 = gx * ty + g1 * cm;
                        const v2f s5 = (g2 * ty) * ty + g1 * cy;
                        q[0].h[hp] = __builtin_amdgcn_cvt_pkrtz(s3.x, s3.y);
                        q[1].h[hp] = __builtin_amdgcn_cvt_pkrtz(s4.x, s4.y);
                        q[2].h[hp] = __builtin_amdgcn_cvt_pkrtz(s5.x, s5.y);
                    }
                    const int ob = j0 >> 3;
                    const int ho = (quad & 1) * 4;
                    #pragma unroll
                    for (int pl = 0; pl < 3; ++pl)
                        *(uint2*)&sS[soct(3 + pl, pmy, ob) + ho] = q[pl].u;
                }
            }
        } else {
            // final: plg1 combines aux + own {cx,cm,cy} with W3; j-reduce
            if (plg == 1) {
                v2f axx = {0.f, 0.f}, axy = {0.f, 0.f}, ayy = {0.f, 0.f};
                #pragma unroll
                for (int mt = 0; mt < 2; ++mt) {
                    const int jb = mt * 16 + quad * 4;
                    const int j0 = jw * 32 + jb;
                    const v4f zv  = *(const v4f*)&sAux[axi(jw, 0, l15, jb)];
                    const v4f txv = *(const v4f*)&sAux[axi(jw, 1, l15, jb)];
                    const v4f tyv = *(const v4f*)&sAux[axi(jw, 2, l15, jb)];
                    const float4 bv = *(const float4*)&b2[j0];
                    const float4 wv = *(const float4*)&W3[j0];
                    #pragma unroll
                    for (int hp = 0; hp < 2; ++hp) {
                        const v2f zb = hp ? (v2f){zv[2], zv[3]}   : (v2f){zv[0], zv[1]};
                        const v2f bb = hp ? (v2f){bv.z, bv.w}     : (v2f){bv.x, bv.y};
                        const v2f w3 = hp ? (v2f){wv.z, wv.w}     : (v2f){wv.x, wv.y};
                        const v2f tx = hp ? (v2f){txv[2], txv[3]} : (v2f){txv[0], txv[1]};
                        const v2f ty = hp ? (v2f){tyv[2], tyv[3]} : (v2f){tyv[0], tyv[1]};
                        const v2f cx = hp ? (v2f){C[mt][0][2], C[mt][0][3]}
                                          : (v2f){C[mt][0][0], C[mt][0][1]};
                        const v2f cm = hp ? (v2f){C[mt][1][2], C[mt][1][3]}
                                          : (v2f){C[mt][1][0], C[mt][1][1]};
                        const v2f cy = hp ? (v2f){C[mt][2][2], C[mt][2][3]}
                                          : (v2f){C[mt][2][0], C[mt][2][1]};
                        v2f g1, g2;
                        tanh_d2_p(zb + bb, g1, g2);
                        const v2f gx = g2 * tx;
                        axx = axx + w3 * (gx * tx + g1 * cx);
                        axy = axy + w3 * (gx * ty + g1 * cm);
                        ayy = ayy + w3 * ((g2 * ty) * ty + g1 * cy);
                    }
                }
                float oxx = axx.x + axx.y, oxy = axy.x + axy.y, oyy = ayy.x + ayy.y;
                // reduce over quads (same p, disjoint j): 2-step butterfly
                oxx += __shfl_xor(oxx, 16); oxx += __shfl_xor(oxx, 32);
                oxy += __shfl_xor(oxy, 16); oxy += __shfl_xor(oxy, 32);
                oyy += __shfl_xor(oyy, 16); oyy += __shfl_xor(oyy, 32);
                // cross-wave (jw) partials: overlay scratch on sS (GEMM done)
                float* sRed = (float*)sS;          // [3][4 jw][16 p] = 768 B
                if (quad == 0) {
                    sRed[0 * 64 + jw * 16 + pmy] = oxx;
                    sRed[1 * 64 + jw * 16 + pmy] = oxy;
                    sRed[2 * 64 + jw * 16 + pmy] = oyy;
                }
            }
            __syncthreads();   // bar D: partials visible
            if (tid < 48) {
                float* sRed = (float*)sS;
                const int c = tid >> 4, p = tid & 15;
                float acc = 0.f;
                #pragma unroll
                for (int jq = 0; jq < 4; ++jq)
                    acc += sRed[c * 64 + jq * 16 + p];
                out[c * N + pbase + p] = acc;
            }
        }
    }
}

extern "C" void kernel_launch(void* const* d_in, const int* in_sizes, int n_in,
                              void* d_out, int out_size, void* d_ws, size_t ws_size,
                              hipStream_t stream) {
    const float* X  = (const float*)d_in[0];
    const float* W0 = (const float*)d_in[1];
    const float* b0 = (const float*)d_in[2];
    const float* W1 = (const float*)d_in[3];
    const float* b1 = (const float*)d_in[4];
    const float* W2 = (const float*)d_in[5];
    const float* b2 = (const float*)d_in[6];
    const float* W3 = (const float*)d_in[7];
    // d_in[8] = b3: constant offset, zero second derivative -> unused.

    const int N = in_sizes[0] / 2;               // 131072 = 8192 * P
    float* out = (float*)d_out;
    _Float16* ws = (_Float16*)d_ws;              // Wt[2][16][128][8] f16 = 64 KB

    hipLaunchKernelGGL(wt_convert, dim3(256), dim3(64), 0, stream, W1, W2, ws);

    hipLaunchKernelGGL(pinn_hess_mfma, dim3(N / P), dim3(NT), 0, stream,
                       X, W0, b0, ws, b1, b2, W3, out, N);
}

// Round 8
// 141.681 us; speedup vs baseline: 1.0699x; 1.0699x over previous
//
#include <hip/hip_runtime.h>

#define H   128
#define P   16             // points per block (= MFMA N)
#define NT  512            // 8 waves: wave = jquad (16 j-rows each)

typedef _Float16 v8h __attribute__((ext_vector_type(8)));
typedef __fp16   h2  __attribute__((ext_vector_type(2)));   // cvt_pkrtz return type
typedef float    v4f __attribute__((ext_vector_type(4)));
typedef float    v2f __attribute__((ext_vector_type(2)));   // -> VOP3P v_pk_*_f32

union PK2 { h2 h[2]; uint2 u; };       // 4 f16 = 8 B

// State plane layout: [pl][p][k], 128 f16 per row, XOR-octet swizzle; returns
// f16 index of octet o of row p. (p&15 == p at P=16.)
__device__ __forceinline__ int soct(int pl, int p, int o) {
    return ((pl * P + p) * 16 + (o ^ (p & 15))) << 3;
}

// Prepass (free): Wt in MFMA A-fragment physical order ws[l][oct][j][8],
// oct = k>>3. Main kernel loads A fragments directly from this buffer into
// registers (64 KB, L2-resident) — A never touches LDS.
__global__ void wt_convert(const float* __restrict__ W1,
                           const float* __restrict__ W2,
                           _Float16* __restrict__ ws) {
    const int t = blockIdx.x * 64 + threadIdx.x;   // 0..16383 (u32 units)
    const int l = t >> 13;
    const int r = t & 8191;
    const int oct = r >> 9;
    const int rem = r & 511;
    const int j  = rem >> 2;
    const int wp = rem & 3;
    const int k  = oct * 8 + 2 * wp;
    const float* __restrict__ W = l ? W2 : W1;
    const float a = W[k * H + j];
    const float b = W[(k + 1) * H + j];
    union { h2 h; unsigned u; } q;
    q.h = __builtin_amdgcn_cvt_pkrtz(a, b);
    ((unsigned*)ws)[t] = q.u;
}

// Packed-pair tanh + derivatives: exp/rcp scalar, fma chain packed (VOP3P).
__device__ __forceinline__ v2f tanh_d2_p(v2f z, v2f& g1, v2f& g2) {
    v2f r;
    r.x = __builtin_amdgcn_rcpf(__expf(2.f * z.x) + 1.f);
    r.y = __builtin_amdgcn_rcpf(__expf(2.f * z.y) + 1.f);
    const v2f a = -2.f * r + 1.f;                  // e=inf -> r=0 -> a=1
    g1 = 1.f - a * a;
    g2 = -2.f * (a * g1);
    return a;
}

// R25 = R23 (proven best, 72.0us) + s_setprio around the GEMM K-loop (T5).
// Evidence table: R17 4w/128-tier 72.3 | R21 reg-A 75.1 | R22 stagger 81.4 |
// R23 8w/64-tier 72.0 | R24 plane-split 100.9. LDS-BW theory refuted (R21/
// R24); occupancy theory refuted (R23: 70% occ, same 72); stagger refuted
// (R22). Corrected accounting at R23: MFMA 60k cy/SIMD (34%), VALU 94k (54%),
// LDS-read 56-85% of ceiling -> multi-pipe dependency floor; the one untried
// lever in the right regime is scheduler arbitration: 6 blocks/CU at
// different phases (the T5-positive case) -> setprio(1) lets GEMM waves
// preempt E-phase waves so the matrix pipe stays fed.
// COMMITMENT: if gain <2%, next round is <<ROOFLINE>>.
__global__ __launch_bounds__(NT, 8)
void pinn_hess_mfma(const float* __restrict__ X,
                    const float* __restrict__ W0, const float* __restrict__ b0,
                    const _Float16* __restrict__ Wt,
                    const float* __restrict__ b1, const float* __restrict__ b2,
                    const float* __restrict__ W3,
                    float* __restrict__ out, int N)
{
    __shared__ _Float16 sS[6 * P * H];        // 24576 B, swizzled state planes

    const int tid   = threadIdx.x;
    const int jquad = tid >> 6;               // wave 0..7 = j range /16
    const int lane  = tid & 63;
    const int quad  = lane >> 4;
    const int l15   = lane & 15;
    const int pbase = blockIdx.x * P;
    const int pmy   = l15;                    // this lane's point row (GEMM n)

    // ---------------- layer 0 (input dim 2, analytic); 512 tasks = 1/thread --
    // task = (point p, j-quad q4): 4 j-values, one uint2 write per plane.
    {
        const int p = tid >> 5, q4 = tid & 31;
        const float x = X[2 * (pbase + p)];
        const float y = X[2 * (pbase + p) + 1];
        const float4 wx4 = *(const float4*)&W0[q4 * 4];
        const float4 wy4 = *(const float4*)&W0[H + q4 * 4];
        const float4 bb4 = *(const float4*)&b0[q4 * 4];
        PK2 q[6];
        #pragma unroll
        for (int hp = 0; hp < 2; ++hp) {       // j-pairs, packed math
            const v2f wx = hp ? (v2f){wx4.z, wx4.w} : (v2f){wx4.x, wx4.y};
            const v2f wy = hp ? (v2f){wy4.z, wy4.w} : (v2f){wy4.x, wy4.y};
            const v2f bb = hp ? (v2f){bb4.z, bb4.w} : (v2f){bb4.x, bb4.y};
            v2f g1, g2;
            const v2f a = tanh_d2_p(x * wx + y * wy + bb, g1, g2);
            const v2f gx = g2 * wx;
            const v2f r0 = a,        r1 = g1 * wx,  r2 = g1 * wy;
            const v2f r3 = gx * wx,  r4 = gx * wy,  r5 = (g2 * wy) * wy;
            q[0].h[hp] = __builtin_amdgcn_cvt_pkrtz(r0.x, r0.y);
            q[1].h[hp] = __builtin_amdgcn_cvt_pkrtz(r1.x, r1.y);
            q[2].h[hp] = __builtin_amdgcn_cvt_pkrtz(r2.x, r2.y);
            q[3].h[hp] = __builtin_amdgcn_cvt_pkrtz(r3.x, r3.y);
            q[4].h[hp] = __builtin_amdgcn_cvt_pkrtz(r4.x, r4.y);
            q[5].h[hp] = __builtin_amdgcn_cvt_pkrtz(r5.x, r5.y);
        }
        const int o  = q4 >> 1;                // octet
        const int ho = (q4 & 1) * 4;           // half-offset within octet
        #pragma unroll
        for (int pl = 0; pl < 6; ++pl)
            *(uint2*)&sS[soct(pl, p, o) + ho] = q[pl].u;
    }

    // A-fragment index (v8h units) for this lane: [oct = kc*4+quad][j][8]
    const int aoff = quad * H + jquad * 16 + l15;   // + kc*4*H
    // hoisted B row term: byte base of (pmy, oct) row is ((pmy*16 + oct^pmy)<<4)
    const int rowb = pmy * 16;

    // ---------------- hidden layers ----------------
    for (int layer = 0; layer < 2; ++layer) {
        const v8h* __restrict__ Ag = (const v8h*)(Wt + layer * (16 * H * 8));

        __syncthreads();   // (1)/(3): sS writes visible

        v4f C[6];
        #pragma unroll
        for (int pl = 0; pl < 6; ++pl) C[pl] = (v4f){0, 0, 0, 0};

        __builtin_amdgcn_s_setprio(1);         // favor GEMM waves on the CU
        #pragma unroll
        for (int kc = 0; kc < 4; ++kc) {
            const v8h A = Ag[aoff + kc * 4 * H];     // L2 hit; TLP hides latency
            const int oct = kc * 4 + quad;
            // per-kc row base hoisted; plane stride 4096 B folds into offset:
            const _Float16* bp = &sS[(rowb + (oct ^ pmy)) << 3];
            #pragma unroll
            for (int pl = 0; pl < 6; ++pl) {
                const v8h B = *(const v8h*)(bp + pl * (P * H));
                C[pl] = __builtin_amdgcn_mfma_f32_16x16x32_f16(A, B, C[pl], 0, 0, 0);
            }
        }
        __builtin_amdgcn_s_setprio(0);

        __syncthreads();   // (2)/(4): all K-loop reads of sS done

        const int j0 = jquad * 16 + quad * 4;        // this lane's 4 j-rows

        if (layer == 0) {
            // packed in-register tanh chain rule; b64 vector writeback
            const float4 bv = *(const float4*)&b1[j0];
            PK2 q[6];
            #pragma unroll
            for (int hp = 0; hp < 2; ++hp) {   // r-pairs (0,1) and (2,3)
                const v2f zb = hp ? (v2f){C[0][2], C[0][3]} : (v2f){C[0][0], C[0][1]};
                const v2f bb = hp ? (v2f){bv.z, bv.w}       : (v2f){bv.x, bv.y};
                const v2f tx = hp ? (v2f){C[1][2], C[1][3]} : (v2f){C[1][0], C[1][1]};
                const v2f ty = hp ? (v2f){C[2][2], C[2][3]} : (v2f){C[2][0], C[2][1]};
                const v2f cx = hp ? (v2f){C[3][2], C[3][3]} : (v2f){C[3][0], C[3][1]};
                const v2f cm = hp ? (v2f){C[4][2], C[4][3]} : (v2f){C[4][0], C[4][1]};
                const v2f cy = hp ? (v2f){C[5][2], C[5][3]} : (v2f){C[5][0], C[5][1]};
                v2f g1, g2;
                const v2f a  = tanh_d2_p(zb + bb, g1, g2);
                const v2f gx = g2 * tx;
                const v2f s0 = a,        s1 = g1 * tx,          s2 = g1 * ty;
                const v2f s3 = gx * tx + g1 * cx;
                const v2f s4 = gx * ty + g1 * cm;
                const v2f s5 = (g2 * ty) * ty + g1 * cy;
                q[0].h[hp] = __builtin_amdgcn_cvt_pkrtz(s0.x, s0.y);
                q[1].h[hp] = __builtin_amdgcn_cvt_pkrtz(s1.x, s1.y);
                q[2].h[hp] = __builtin_amdgcn_cvt_pkrtz(s2.x, s2.y);
                q[3].h[hp] = __builtin_amdgcn_cvt_pkrtz(s3.x, s3.y);
                q[4].h[hp] = __builtin_amdgcn_cvt_pkrtz(s4.x, s4.y);
                q[5].h[hp] = __builtin_amdgcn_cvt_pkrtz(s5.x, s5.y);
            }
            const int ob = j0 >> 3;            // octet of j0
            const int ho = (quad & 1) * 4;     // half-offset within octet
            #pragma unroll
            for (int pl = 0; pl < 6; ++pl)
                *(uint2*)&sS[soct(pl, pmy, ob) + ho] = q[pl].u;
        } else {
            // final combine + W3 dot, packed; reduce j over quads then jquads
            v2f axx = {0.f, 0.f}, axy = {0.f, 0.f}, ayy = {0.f, 0.f};
            const float4 bv = *(const float4*)&b2[j0];
            const float4 wv = *(const float4*)&W3[j0];
            #pragma unroll
            for (int hp = 0; hp < 2; ++hp) {
                const v2f zb = hp ? (v2f){C[0][2], C[0][3]} : (v2f){C[0][0], C[0][1]};
                const v2f bb = hp ? (v2f){bv.z, bv.w}       : (v2f){bv.x, bv.y};
                const v2f w3 = hp ? (v2f){wv.z, wv.w}       : (v2f){wv.x, wv.y};
                const v2f tx = hp ? (v2f){C[1][2], C[1][3]} : (v2f){C[1][0], C[1][1]};
                const v2f ty = hp ? (v2f){C[2][2], C[2][3]} : (v2f){C[2][0], C[2][1]};
                const v2f cx = hp ? (v2f){C[3][2], C[3][3]} : (v2f){C[3][0], C[3][1]};
                const v2f cm = hp ? (v2f){C[4][2], C[4][3]} : (v2f){C[4][0], C[4][1]};
                const v2f cy = hp ? (v2f){C[5][2], C[5][3]} : (v2f){C[5][0], C[5][1]};
                v2f g1, g2;
                tanh_d2_p(zb + bb, g1, g2);
                const v2f gx = g2 * tx;
                axx = axx + w3 * (gx * tx + g1 * cx);
                axy = axy + w3 * (gx * ty + g1 * cm);
                ayy = ayy + w3 * ((g2 * ty) * ty + g1 * cy);
            }
            float oxx = axx.x + axx.y, oxy = axy.x + axy.y, oyy = ayy.x + ayy.y;
            // reduce over quads (same p, disjoint j): 2-step butterfly
            oxx += __shfl_xor(oxx, 16); oxx += __shfl_xor(oxx, 32);
            oxy += __shfl_xor(oxy, 16); oxy += __shfl_xor(oxy, 32);
            oyy += __shfl_xor(oyy, 16); oyy += __shfl_xor(oyy, 32);
            // cross-wave (jquad) partials: overlay scratch on sS (all reads
            // of sS finished at barrier (4) above)
            float* sRed = (float*)sS;              // [3][8 jquad][16 p] = 1.5 KB
            if (quad == 0) {
                sRed[0 * 128 + jquad * 16 + pmy] = oxx;
                sRed[1 * 128 + jquad * 16 + pmy] = oxy;
                sRed[2 * 128 + jquad * 16 + pmy] = oyy;
            }
            __syncthreads();   // (5) partials visible
            if (tid < 48) {
                const int c = tid >> 4, p = tid & 15;
                float acc = 0.f;
                #pragma unroll
                for (int jq = 0; jq < 8; ++jq)
                    acc += sRed[c * 128 + jq * 16 + p];
                out[c * N + pbase + p] = acc;
            }
        }
    }
}

extern "C" void kernel_launch(void* const* d_in, const int* in_sizes, int n_in,
                              void* d_out, int out_size, void* d_ws, size_t ws_size,
                              hipStream_t stream) {
    const float* X  = (const float*)d_in[0];
    const float* W0 = (const float*)d_in[1];
    const float* b0 = (const float*)d_in[2];
    const float* W1 = (const float*)d_in[3];
    const float* b1 = (const float*)d_in[4];
    const float* W2 = (const float*)d_in[5];
    const float* b2 = (const float*)d_in[6];
    const float* W3 = (const float*)d_in[7];
    // d_in[8] = b3: constant offset, zero second derivative -> unused.

    const int N = in_sizes[0] / 2;               // 131072 = 8192 * P
    float* out = (float*)d_out;
    _Float16* ws = (_Float16*)d_ws;              // Wt[2][16][128][8] f16 = 64 KB

    hipLaunchKernelGGL(wt_convert, dim3(256), dim3(64), 0, stream, W1, W2, ws);

    hipLaunchKernelGGL(pinn_hess_mfma, dim3(N / P), dim3(NT), 0, stream,
                       X, W0, b0, ws, b1, b2, W3, out, N);
}